// Round 1
// baseline (711.188 us; speedup 1.0000x reference)
//
#include <hip/hip_runtime.h>
#include <hip/hip_bf16.h>

// GCN forward on MI355X — round 6: latency-tolerant 16-row/wave MFMA GEMMs.
//
//   w1t = bf16(w1^T) [128][512], w2t = bf16(w2^T) [64][128]
//   CSR build: zero -> hist -> scanA/B/C -> scatter (int2 edges)
//   h0b = bf16(x@w1 + b1)    via MFMA (16 rows/wave, full unroll, in-place B reload)
//   h1r = bf16(relu(spmm(A, h0b)))
//   h2  = h1r@w2t + b2       via MFMA (16 rows/wave, all A+B batched up front)
//   out = spmm(A, h2)

constexpr int N_NODES = 100000;
constexpr int IN_F    = 512;
constexpr int HID_F   = 128;
constexpr int N_CLS   = 64;
constexpr int N_EDGES = 1600000;

constexpr int SCAN_BLOCK    = 256;
constexpr int N_SCAN_BLOCKS = (N_NODES + SCAN_BLOCK - 1) / SCAN_BLOCK;  // 391
constexpr int N_WAVES_G16   = N_NODES / 16;                             // 6250

typedef __attribute__((ext_vector_type(8))) short short8;
typedef __attribute__((ext_vector_type(4))) float f32x4;

static __device__ __forceinline__ unsigned short f2bf(float x) {
    unsigned int u = __float_as_uint(x);
    unsigned int r = (u + 0x7FFFu + ((u >> 16) & 1u)) >> 16;   // RNE
    return (unsigned short)r;
}
static __device__ __forceinline__ float bf2f(unsigned short u) {
    return __uint_as_float(((unsigned int)u) << 16);
}

// ---------------- weight transposes -> bf16 ----------------
__global__ void w1t_kernel(const float* __restrict__ w1, unsigned short* __restrict__ w1t)
{
    int idx = blockIdx.x * 256 + threadIdx.x;      // 65536 = 128*512, n-major
    int n = idx >> 9, k = idx & 511;
    w1t[idx] = f2bf(w1[k * HID_F + n]);
}

__global__ void w2t_kernel(const float* __restrict__ w2, unsigned short* __restrict__ w2t)
{
    int idx = blockIdx.x * 256 + threadIdx.x;      // 8192 = 64*128, n-major
    int n = idx >> 7, k = idx & 127;
    w2t[idx] = f2bf(w2[k * N_CLS + n]);
}

// ---------------- CSR build ----------------
__global__ void zero_int_kernel(int* __restrict__ p, int n)
{
    int i = blockIdx.x * blockDim.x + threadIdx.x;
    if (i < n) p[i] = 0;
}

__global__ void hist_kernel(const int* __restrict__ row, int* __restrict__ counts)
{
    int e = blockIdx.x * blockDim.x + threadIdx.x;
    if (e < N_EDGES) atomicAdd(&counts[row[e]], 1);
}

__global__ __launch_bounds__(SCAN_BLOCK) void scanA_kernel(
    const int* __restrict__ counts, int* __restrict__ local_ex,
    int* __restrict__ blockSums)
{
    __shared__ int s[SCAN_BLOCK];
    const int t = threadIdx.x;
    const int i = blockIdx.x * SCAN_BLOCK + t;
    int v = (i < N_NODES) ? counts[i] : 0;
    s[t] = v;
    __syncthreads();
    for (int off = 1; off < SCAN_BLOCK; off <<= 1) {
        int u = (t >= off) ? s[t - off] : 0;
        __syncthreads();
        s[t] += u;
        __syncthreads();
    }
    if (i < N_NODES) local_ex[i] = s[t] - v;
    if (t == SCAN_BLOCK - 1) blockSums[blockIdx.x] = s[t];
}

__global__ __launch_bounds__(512) void scanB_kernel(int* __restrict__ blockSums)
{
    __shared__ int s[512];
    const int t = threadIdx.x;
    int v = (t < N_SCAN_BLOCKS) ? blockSums[t] : 0;
    s[t] = v;
    __syncthreads();
    for (int off = 1; off < 512; off <<= 1) {
        int u = (t >= off) ? s[t - off] : 0;
        __syncthreads();
        s[t] += u;
        __syncthreads();
    }
    if (t < N_SCAN_BLOCKS) blockSums[t] = s[t] - v;
}

__global__ __launch_bounds__(SCAN_BLOCK) void scanC_kernel(
    const int* __restrict__ local_ex, const int* __restrict__ blockSums,
    int* __restrict__ row_ptr, int* __restrict__ cursor)
{
    const int i = blockIdx.x * SCAN_BLOCK + threadIdx.x;
    if (i < N_NODES) {
        int v = local_ex[i] + blockSums[blockIdx.x];
        row_ptr[i] = v;
        cursor[i]  = v;
    }
    if (i == 0) row_ptr[N_NODES] = N_EDGES;
}

__global__ void scatter_kernel(
    const int* __restrict__ row, const int* __restrict__ col,
    const float* __restrict__ val, int* __restrict__ cursor,
    int2* __restrict__ es)
{
    int e = blockIdx.x * blockDim.x + threadIdx.x;
    if (e < N_EDGES) {
        int pos = atomicAdd(&cursor[row[e]], 1);
        es[pos] = make_int2(col[e], __float_as_int(val[e]));
    }
}

// ---------------- GEMM1 via MFMA: h0b = bf16(x @ w1 + b1) -------------------
// 16 rows per wave (6250 waves -> ~24 waves/CU demanded, 16 resident at
// launch_bounds(256,4)). Full K unroll; A double-buffered one K-tile ahead;
// each B-frag reloaded IN PLACE right after its last use so every B load has
// a full iteration of latency cover while keeping B at ~36 VGPRs.
__global__ __launch_bounds__(256, 4) void gemm1_mfma_kernel(
    const float* __restrict__ x, const unsigned short* __restrict__ w1t,
    const float* __restrict__ b1, unsigned short* __restrict__ h0b)
{
    const int lane = threadIdx.x & 63;
    const int wid  = blockIdx.x * 4 + (threadIdx.x >> 6);
    if (wid >= N_WAVES_G16) return;
    const int row0 = wid * 16;
    const int m = lane & 15;
    const int q = lane >> 4;

    f32x4 acc[8];
#pragma unroll
    for (int ni = 0; ni < 8; ++ni)
        acc[ni] = (f32x4){0.f, 0.f, 0.f, 0.f};

    union U8 { short8 v; __hip_bfloat162 h[4]; };

    const float* ap = x + (size_t)(row0 + m) * IN_F + q * 8;
    const unsigned short* bp = w1t + (size_t)m * IN_F + q * 8;

    // preload K-tile 0: A (2 float4) + all 8 B-frags
    float4 a_cur_l = ((const float4*)ap)[0];
    float4 a_cur_h = ((const float4*)ap)[1];
    short8 bf[8];
#pragma unroll
    for (int ni = 0; ni < 8; ++ni)
        bf[ni] = *(const short8*)(bp + (size_t)ni * 16 * IN_F);

#pragma unroll
    for (int t = 0; t < 16; ++t) {          // kk = t*32, fully unrolled
        // prefetch next A tile (HBM) before touching current data
        float4 a_nxt_l, a_nxt_h;
        if (t + 1 < 16) {
            a_nxt_l = ((const float4*)(ap + (t + 1) * 32))[0];
            a_nxt_h = ((const float4*)(ap + (t + 1) * 32))[1];
        }

        // convert current A to bf16 frag (VALU, covers part of load latency)
        U8 u;
        u.h[0] = __float22bfloat162_rn(make_float2(a_cur_l.x, a_cur_l.y));
        u.h[1] = __float22bfloat162_rn(make_float2(a_cur_l.z, a_cur_l.w));
        u.h[2] = __float22bfloat162_rn(make_float2(a_cur_h.x, a_cur_h.y));
        u.h[3] = __float22bfloat162_rn(make_float2(a_cur_h.z, a_cur_h.w));
        short8 a = u.v;

#pragma unroll
        for (int ni = 0; ni < 8; ++ni) {
            acc[ni] = __builtin_amdgcn_mfma_f32_16x16x32_bf16(a, bf[ni], acc[ni], 0, 0, 0);
            if (t + 1 < 16)     // consume-then-reload: next-tile B issued now,
                bf[ni] = *(const short8*)(bp + (size_t)ni * 16 * IN_F + (t + 1) * 32);
        }

        a_cur_l = a_nxt_l; a_cur_h = a_nxt_h;
    }

    float bias[8];
#pragma unroll
    for (int ni = 0; ni < 8; ++ni) bias[ni] = b1[ni * 16 + m];

#pragma unroll
    for (int r = 0; r < 4; ++r) {
        int row = row0 + q * 4 + r;
        unsigned short* dst = h0b + (size_t)row * HID_F;
#pragma unroll
        for (int ni = 0; ni < 8; ++ni)
            dst[ni * 16 + m] = f2bf(acc[ni][r] + bias[ni]);
    }
}

// ---------------- GEMM2 via MFMA: h2 = h1r @ w2 + b2 ------------------------
// 16 rows/wave. w2t is 16 KB (L2-resident): the wave's ENTIRE B (16 frags)
// and entire A slab (4 frags) are batch-issued up front -> one load burst,
// one MFMA burst, no per-iter stalls.
__global__ __launch_bounds__(256, 4) void gemm2_mfma_kernel(
    const unsigned short* __restrict__ h1r, const unsigned short* __restrict__ w2t,
    const float* __restrict__ b2, float* __restrict__ h2)
{
    const int lane = threadIdx.x & 63;
    const int wid  = blockIdx.x * 4 + (threadIdx.x >> 6);
    if (wid >= N_WAVES_G16) return;
    const int row0 = wid * 16;
    const int m = lane & 15;
    const int q = lane >> 4;

    const unsigned short* ap = h1r + (size_t)(row0 + m) * HID_F + q * 8;
    const unsigned short* bp = w2t + (size_t)m * HID_F + q * 8;

    short8 a[4];
#pragma unroll
    for (int t = 0; t < 4; ++t)
        a[t] = *(const short8*)(ap + t * 32);

    short8 b[4][4];
#pragma unroll
    for (int ni = 0; ni < 4; ++ni)
#pragma unroll
        for (int t = 0; t < 4; ++t)
            b[ni][t] = *(const short8*)(bp + (size_t)ni * 16 * HID_F + t * 32);

    f32x4 acc[4];
#pragma unroll
    for (int ni = 0; ni < 4; ++ni)
        acc[ni] = (f32x4){0.f, 0.f, 0.f, 0.f};

#pragma unroll
    for (int t = 0; t < 4; ++t)             // same K order as before (numerics)
#pragma unroll
        for (int ni = 0; ni < 4; ++ni)
            acc[ni] = __builtin_amdgcn_mfma_f32_16x16x32_bf16(a[t], b[ni][t], acc[ni], 0, 0, 0);

    float bias[4];
#pragma unroll
    for (int ni = 0; ni < 4; ++ni) bias[ni] = b2[ni * 16 + m];

#pragma unroll
    for (int r = 0; r < 4; ++r) {
        int row = row0 + q * 4 + r;
        float* dst = h2 + (size_t)row * N_CLS;
#pragma unroll
        for (int ni = 0; ni < 4; ++ni)
            dst[ni * 16 + m] = acc[ni][r] + bias[ni];
    }
}

// ---------------- SpMM1 gather: h1r = bf16(relu(sum val*h0b[col])) ----------
__global__ __launch_bounds__(256) void spmm_g128_kernel(
    const int* __restrict__ rp, const int2* __restrict__ es,
    const unsigned short* __restrict__ src, unsigned short* __restrict__ dst)
{
    const int r = blockIdx.x * 4 + threadIdx.y;
    if (r >= N_NODES) return;
    const int lane = threadIdx.x;
    const int j0 = rp[r], j1 = rp[r + 1];

    float ax = 0.f, ay = 0.f;
    int j = j0;
    for (; j + 7 < j1; j += 8) {        // 8 gathers in flight
        int2 e[8];
        ushort2 u[8];
#pragma unroll
        for (int t = 0; t < 8; ++t) e[t] = es[j + t];
#pragma unroll
        for (int t = 0; t < 8; ++t)
            u[t] = ((const ushort2*)(src + (size_t)e[t].x * HID_F))[lane];
#pragma unroll
        for (int t = 0; t < 8; ++t) {
            float v = __int_as_float(e[t].y);
            ax += v * bf2f(u[t].x);
            ay += v * bf2f(u[t].y);
        }
    }
    if (j + 3 < j1) {
        int2 e[4];
        ushort2 u[4];
#pragma unroll
        for (int t = 0; t < 4; ++t) e[t] = es[j + t];
#pragma unroll
        for (int t = 0; t < 4; ++t)
            u[t] = ((const ushort2*)(src + (size_t)e[t].x * HID_F))[lane];
#pragma unroll
        for (int t = 0; t < 4; ++t) {
            float v = __int_as_float(e[t].y);
            ax += v * bf2f(u[t].x);
            ay += v * bf2f(u[t].y);
        }
        j += 4;
    }
    for (; j < j1; ++j) {
        int2 e = es[j];
        float v = __int_as_float(e.y);
        ushort2 u = ((const ushort2*)(src + (size_t)e.x * HID_F))[lane];
        ax += v * bf2f(u.x);
        ay += v * bf2f(u.y);
    }
    ushort2 o;
    o.x = f2bf(fmaxf(ax, 0.f));
    o.y = f2bf(fmaxf(ay, 0.f));
    ((ushort2*)(dst + (size_t)r * HID_F))[lane] = o;
}

// ---------------- SpMM2 gather (F=64) ----------------
__global__ __launch_bounds__(256) void spmm_g64_kernel(
    const int* __restrict__ rp, const int2* __restrict__ es,
    const float* __restrict__ src, float* __restrict__ dst)
{
    const int r = blockIdx.x * 4 + threadIdx.y;
    if (r >= N_NODES) return;
    const int lane = threadIdx.x;
    const int j0 = rp[r], j1 = rp[r + 1];

    float acc = 0.f;
    int j = j0;
    for (; j + 7 < j1; j += 8) {
        int2 e[8];
        float a[8];
#pragma unroll
        for (int t = 0; t < 8; ++t) e[t] = es[j + t];
#pragma unroll
        for (int t = 0; t < 8; ++t)
            a[t] = src[(size_t)e[t].x * N_CLS + lane];
#pragma unroll
        for (int t = 0; t < 8; ++t)
            acc += __int_as_float(e[t].y) * a[t];
    }
    if (j + 3 < j1) {
        int2 e[4];
        float a[4];
#pragma unroll
        for (int t = 0; t < 4; ++t) e[t] = es[j + t];
#pragma unroll
        for (int t = 0; t < 4; ++t)
            a[t] = src[(size_t)e[t].x * N_CLS + lane];
#pragma unroll
        for (int t = 0; t < 4; ++t)
            acc += __int_as_float(e[t].y) * a[t];
        j += 4;
    }
    for (; j < j1; ++j) {
        int2 e = es[j];
        acc += __int_as_float(e.y) * src[(size_t)e.x * N_CLS + lane];
    }
    dst[(size_t)r * N_CLS + lane] = acc;
}

extern "C" void kernel_launch(void* const* d_in, const int* in_sizes, int n_in,
                              void* d_out, int out_size, void* d_ws, size_t ws_size,
                              hipStream_t stream)
{
    const float* x       = (const float*)d_in[0];
    const int*   adj_row = (const int*)  d_in[1];
    const int*   adj_col = (const int*)  d_in[2];
    const float* adj_val = (const float*)d_in[3];
    const float* w1      = (const float*)d_in[4];
    const float* b1      = (const float*)d_in[5];
    const float* w2      = (const float*)d_in[6];
    const float* b2      = (const float*)d_in[7];
    float*       out     = (float*)d_out;

    // workspace carve-up
    char* ws = (char*)d_ws;
    unsigned short* h0b   = (unsigned short*)ws;                  // 25.6 MB
    unsigned short* h1r   = (unsigned short*)(ws + 25600000);     // 25.6 MB
    float*          h2    = (float*)(ws + 51200000);              // 25.6 MB
    int2*           es    = (int2*) (ws + 76800000);              // 12.8 MB
    int*            rp    = (int*)  (ws + 89600000);              // 400 KB + 4
    int*            cur   = (int*)  (ws + 90000016);              // 400 KB
    unsigned short* w1t   = (unsigned short*)(ws + 90400016);     // 128 KB
    int*            lex   = (int*)  (ws + 90531088);              // 400 KB
    int*            bsum  = (int*)  (ws + 90931088);              // ~1.6 KB
    unsigned short* w2t   = (unsigned short*)(ws + 90932656);     // 16 KB

    // ---- prep ----
    w1t_kernel<<<IN_F * HID_F / 256, 256, 0, stream>>>(w1, w1t);
    w2t_kernel<<<HID_F * N_CLS / 256, 256, 0, stream>>>(w2, w2t);
    zero_int_kernel<<<(N_NODES + 255) / 256, 256, 0, stream>>>(cur, N_NODES);
    hist_kernel<<<(N_EDGES + 255) / 256, 256, 0, stream>>>(adj_row, cur);
    scanA_kernel<<<N_SCAN_BLOCKS, SCAN_BLOCK, 0, stream>>>(cur, lex, bsum);
    scanB_kernel<<<1, 512, 0, stream>>>(bsum);
    scanC_kernel<<<N_SCAN_BLOCKS, SCAN_BLOCK, 0, stream>>>(lex, bsum, rp, cur);
    scatter_kernel<<<(N_EDGES + 255) / 256, 256, 0, stream>>>(
        adj_row, adj_col, adj_val, cur, es);

    // ---- conv1 ----
    gemm1_mfma_kernel<<<(N_WAVES_G16 + 3) / 4, 256, 0, stream>>>(x, w1t, b1, h0b);
    spmm_g128_kernel<<<(N_NODES + 3) / 4, dim3(64, 4), 0, stream>>>(
        rp, es, h0b, h1r);

    // ---- conv2 ----
    gemm2_mfma_kernel<<<(N_WAVES_G16 + 3) / 4, 256, 0, stream>>>(h1r, w2t, b2, h2);
    spmm_g64_kernel<<<(N_NODES + 3) / 4, dim3(64, 4), 0, stream>>>(
        rp, es, h2, out);
}

// Round 2
// 660.080 us; speedup vs baseline: 1.0774x; 1.0774x over previous
//
#include <hip/hip_runtime.h>
#include <hip/hip_bf16.h>

// GCN forward on MI355X — round 7: LDS-staged B for both MFMA GEMMs.
//
// Key structural fix vs round 6: B-weight loads move from global (vmcnt) to
// LDS (lgkmcnt). Global A-loads (HBM) and B-reads no longer share the in-order
// vmcnt queue, so per-iter B waits stop queueing behind ~900-cycle HBM A
// prefetches. Also collapses w1t L2 re-read traffic 800 MB -> 50 MB.
//
//   w1t = bf16(w1^T) [128][512], w2t = bf16(w2^T) [64][128]
//   CSR build: zero -> hist -> scanA/B/C -> scatter (int2 edges)
//   h0b = bf16(x@w1 + b1)    MFMA, B in LDS (2 x 64KB K-phases), 8 waves/block
//   h1r = bf16(relu(spmm(A, h0b)))
//   h2  = h1r@w2t + b2       MFMA, B in LDS (16KB), batched A
//   out = spmm(A, h2)

constexpr int N_NODES = 100000;
constexpr int IN_F    = 512;
constexpr int HID_F   = 128;
constexpr int N_CLS   = 64;
constexpr int N_EDGES = 1600000;

constexpr int SCAN_BLOCK    = 256;
constexpr int N_SCAN_BLOCKS = (N_NODES + SCAN_BLOCK - 1) / SCAN_BLOCK;  // 391
constexpr int NB_GEMM       = (N_NODES + 255) / 256;                    // 391

typedef __attribute__((ext_vector_type(8))) short short8;
typedef __attribute__((ext_vector_type(4))) float f32x4;

static __device__ __forceinline__ unsigned short f2bf(float x) {
    unsigned int u = __float_as_uint(x);
    unsigned int r = (u + 0x7FFFu + ((u >> 16) & 1u)) >> 16;   // RNE
    return (unsigned short)r;
}
static __device__ __forceinline__ float bf2f(unsigned short u) {
    return __uint_as_float(((unsigned int)u) << 16);
}

// ---------------- weight transposes -> bf16 ----------------
__global__ void w1t_kernel(const float* __restrict__ w1, unsigned short* __restrict__ w1t)
{
    int idx = blockIdx.x * 256 + threadIdx.x;      // 65536 = 128*512, n-major
    int n = idx >> 9, k = idx & 511;
    w1t[idx] = f2bf(w1[k * HID_F + n]);
}

__global__ void w2t_kernel(const float* __restrict__ w2, unsigned short* __restrict__ w2t)
{
    int idx = blockIdx.x * 256 + threadIdx.x;      // 8192 = 64*128, n-major
    int n = idx >> 7, k = idx & 127;
    w2t[idx] = f2bf(w2[k * N_CLS + n]);
}

// ---------------- CSR build ----------------
__global__ void zero_int_kernel(int* __restrict__ p, int n)
{
    int i = blockIdx.x * blockDim.x + threadIdx.x;
    if (i < n) p[i] = 0;
}

__global__ void hist_kernel(const int* __restrict__ row, int* __restrict__ counts)
{
    int e = blockIdx.x * blockDim.x + threadIdx.x;
    if (e < N_EDGES) atomicAdd(&counts[row[e]], 1);
}

__global__ __launch_bounds__(SCAN_BLOCK) void scanA_kernel(
    const int* __restrict__ counts, int* __restrict__ local_ex,
    int* __restrict__ blockSums)
{
    __shared__ int s[SCAN_BLOCK];
    const int t = threadIdx.x;
    const int i = blockIdx.x * SCAN_BLOCK + t;
    int v = (i < N_NODES) ? counts[i] : 0;
    s[t] = v;
    __syncthreads();
    for (int off = 1; off < SCAN_BLOCK; off <<= 1) {
        int u = (t >= off) ? s[t - off] : 0;
        __syncthreads();
        s[t] += u;
        __syncthreads();
    }
    if (i < N_NODES) local_ex[i] = s[t] - v;
    if (t == SCAN_BLOCK - 1) blockSums[blockIdx.x] = s[t];
}

__global__ __launch_bounds__(512) void scanB_kernel(int* __restrict__ blockSums)
{
    __shared__ int s[512];
    const int t = threadIdx.x;
    int v = (t < N_SCAN_BLOCKS) ? blockSums[t] : 0;
    s[t] = v;
    __syncthreads();
    for (int off = 1; off < 512; off <<= 1) {
        int u = (t >= off) ? s[t - off] : 0;
        __syncthreads();
        s[t] += u;
        __syncthreads();
    }
    if (t < N_SCAN_BLOCKS) blockSums[t] = s[t] - v;
}

__global__ __launch_bounds__(SCAN_BLOCK) void scanC_kernel(
    const int* __restrict__ local_ex, const int* __restrict__ blockSums,
    int* __restrict__ row_ptr, int* __restrict__ cursor)
{
    const int i = blockIdx.x * SCAN_BLOCK + threadIdx.x;
    if (i < N_NODES) {
        int v = local_ex[i] + blockSums[blockIdx.x];
        row_ptr[i] = v;
        cursor[i]  = v;
    }
    if (i == 0) row_ptr[N_NODES] = N_EDGES;
}

__global__ void scatter_kernel(
    const int* __restrict__ row, const int* __restrict__ col,
    const float* __restrict__ val, int* __restrict__ cursor,
    int2* __restrict__ es)
{
    int e = blockIdx.x * blockDim.x + threadIdx.x;
    if (e < N_EDGES) {
        int pos = atomicAdd(&cursor[row[e]], 1);
        es[pos] = make_int2(col[e], __float_as_int(val[e]));
    }
}

// ---------------- GEMM1 via MFMA: h0b = bf16(x @ w1 + b1) -------------------
// 512 threads = 8 waves x 32 rows = 256 rows/block, grid 391.
// B (w1t) staged in LDS in two 64 KB K-phases, XOR-swizzled ((n&7)<<4) so the
// per-frag ds_read_b128 (row stride 512 B) isn't a same-bank pileup.
// A streams from HBM with a 1-iter register prefetch; B consumption is pure
// lgkmcnt -> no vmcnt cross-serialization with the HBM A stream.
__global__ __launch_bounds__(512, 4) void gemm1_mfma_kernel(
    const float* __restrict__ x, const unsigned short* __restrict__ w1t,
    const float* __restrict__ b1, unsigned short* __restrict__ h0b)
{
    __shared__ unsigned short Bs[128 * 256];       // 64 KB
    char* lb = (char*)Bs;

    const int tid  = threadIdx.x;
    const int lane = tid & 63;
    const int w    = tid >> 6;                     // 0..7
    const int m = lane & 15;
    const int q = lane >> 4;
    const int row0 = blockIdx.x * 256 + w * 32;
    const bool active = row0 < N_NODES;            // N_NODES % 32 == 0

    f32x4 acc[2][8];
#pragma unroll
    for (int mi = 0; mi < 2; ++mi)
#pragma unroll
        for (int ni = 0; ni < 8; ++ni)
            acc[mi][ni] = (f32x4){0.f, 0.f, 0.f, 0.f};

    union U8 { short8 v; __hip_bfloat162 h[4]; };

    const float* a0p = x + (size_t)(row0 + m)      * IN_F + q * 8;
    const float* a1p = x + (size_t)(row0 + 16 + m) * IN_F + q * 8;
    const int swz = (m & 7) << 4;

    for (int p = 0; p < 2; ++p) {
        // ---- stage B half-K into LDS: k in [p*256, p*256+256), all 128 n ----
        {
            const unsigned short* src = w1t + p * 256;
#pragma unroll
            for (int i = 0; i < 8; ++i) {
                int chunk = tid + i * 512;         // 0..4095
                int n   = chunk >> 5;              // 32 chunks per n-row
                int k16 = chunk & 31;
                short8 v = *(const short8*)(src + (size_t)n * IN_F + k16 * 8);
                *(short8*)(lb + ((n * 512 + k16 * 16) ^ ((n & 7) << 4))) = v;
            }
        }
        __syncthreads();

        if (active) {
            const float* a0 = a0p + p * 256;
            const float* a1 = a1p + p * 256;
            float4 c0l = ((const float4*)a0)[0];
            float4 c0h = ((const float4*)a0)[1];
            float4 c1l = ((const float4*)a1)[0];
            float4 c1h = ((const float4*)a1)[1];

#pragma unroll
            for (int t = 0; t < 8; ++t) {          // local k-tile = t*32
                // prefetch next A tile (HBM) before the MFMA section
                float4 n0l, n0h, n1l, n1h;
                if (t + 1 < 8) {
                    n0l = ((const float4*)(a0 + (t + 1) * 32))[0];
                    n0h = ((const float4*)(a0 + (t + 1) * 32))[1];
                    n1l = ((const float4*)(a1 + (t + 1) * 32))[0];
                    n1h = ((const float4*)(a1 + (t + 1) * 32))[1];
                }

                U8 u0, u1;
                u0.h[0] = __float22bfloat162_rn(make_float2(c0l.x, c0l.y));
                u0.h[1] = __float22bfloat162_rn(make_float2(c0l.z, c0l.w));
                u0.h[2] = __float22bfloat162_rn(make_float2(c0h.x, c0h.y));
                u0.h[3] = __float22bfloat162_rn(make_float2(c0h.z, c0h.w));
                u1.h[0] = __float22bfloat162_rn(make_float2(c1l.x, c1l.y));
                u1.h[1] = __float22bfloat162_rn(make_float2(c1l.z, c1l.w));
                u1.h[2] = __float22bfloat162_rn(make_float2(c1h.x, c1h.y));
                u1.h[3] = __float22bfloat162_rn(make_float2(c1h.z, c1h.w));
                short8 av0 = u0.v, av1 = u1.v;

                const int kb = t * 64 + q * 16;    // byte offset of k within row
#pragma unroll
                for (int ni = 0; ni < 8; ++ni) {
                    int off = (((ni * 16 + m) * 512) + kb) ^ swz;
                    short8 bfr = *(const short8*)(lb + off);
                    acc[0][ni] = __builtin_amdgcn_mfma_f32_16x16x32_bf16(av0, bfr, acc[0][ni], 0, 0, 0);
                    acc[1][ni] = __builtin_amdgcn_mfma_f32_16x16x32_bf16(av1, bfr, acc[1][ni], 0, 0, 0);
                }

                c0l = n0l; c0h = n0h; c1l = n1l; c1h = n1h;
            }
        }
        __syncthreads();                           // before next phase overwrites Bs
    }

    if (!active) return;

    float bias[8];
#pragma unroll
    for (int ni = 0; ni < 8; ++ni) bias[ni] = b1[ni * 16 + m];

#pragma unroll
    for (int mi = 0; mi < 2; ++mi)
#pragma unroll
        for (int r = 0; r < 4; ++r) {
            int row = row0 + mi * 16 + q * 4 + r;
            unsigned short* dst = h0b + (size_t)row * HID_F;
#pragma unroll
            for (int ni = 0; ni < 8; ++ni)
                dst[ni * 16 + m] = f2bf(acc[mi][ni][r] + bias[ni]);
        }
}

// ---------------- GEMM2 via MFMA: h2 = h1r @ w2 + b2 ------------------------
// Same structure: w2t (16 KB) staged once in LDS; A (h1r, bf16) batch-loaded
// into registers up front (one vmcnt drain); MFMA reads B via lgkmcnt.
__global__ __launch_bounds__(512, 4) void gemm2_mfma_kernel(
    const unsigned short* __restrict__ h1r, const unsigned short* __restrict__ w2t,
    const float* __restrict__ b2, float* __restrict__ h2)
{
    __shared__ unsigned short Bs[64 * 128];        // 16 KB
    char* lb = (char*)Bs;

    const int tid  = threadIdx.x;
    const int lane = tid & 63;
    const int w    = tid >> 6;
    const int m = lane & 15;
    const int q = lane >> 4;
    const int row0 = blockIdx.x * 256 + w * 32;
    const bool active = row0 < N_NODES;

    // ---- stage w2t into LDS: [n=64][k=128], XOR ((n&7)<<4) ----
#pragma unroll
    for (int i = 0; i < 2; ++i) {
        int chunk = tid + i * 512;                 // 0..1023
        int n   = chunk >> 4;                      // 16 chunks per n-row
        int k16 = chunk & 15;
        short8 v = *(const short8*)(w2t + (size_t)n * HID_F + k16 * 8);
        *(short8*)(lb + ((n * 256 + k16 * 16) ^ ((n & 7) << 4))) = v;
    }
    __syncthreads();
    if (!active) return;                           // no barriers after this

    const unsigned short* a0p = h1r + (size_t)(row0 + m)      * HID_F + q * 8;
    const unsigned short* a1p = h1r + (size_t)(row0 + 16 + m) * HID_F + q * 8;

    short8 a0[4], a1[4];
#pragma unroll
    for (int t = 0; t < 4; ++t) {
        a0[t] = *(const short8*)(a0p + t * 32);
        a1[t] = *(const short8*)(a1p + t * 32);
    }

    f32x4 acc[2][4];
#pragma unroll
    for (int mi = 0; mi < 2; ++mi)
#pragma unroll
        for (int ni = 0; ni < 4; ++ni)
            acc[mi][ni] = (f32x4){0.f, 0.f, 0.f, 0.f};

    const int swz = (m & 7) << 4;
#pragma unroll
    for (int t = 0; t < 4; ++t) {
        const int kb = t * 64 + q * 16;
#pragma unroll
        for (int ni = 0; ni < 4; ++ni) {
            int off = (((ni * 16 + m) * 256) + kb) ^ swz;
            short8 b = *(const short8*)(lb + off);
            acc[0][ni] = __builtin_amdgcn_mfma_f32_16x16x32_bf16(a0[t], b, acc[0][ni], 0, 0, 0);
            acc[1][ni] = __builtin_amdgcn_mfma_f32_16x16x32_bf16(a1[t], b, acc[1][ni], 0, 0, 0);
        }
    }

    float bias[4];
#pragma unroll
    for (int ni = 0; ni < 4; ++ni) bias[ni] = b2[ni * 16 + m];

#pragma unroll
    for (int mi = 0; mi < 2; ++mi)
#pragma unroll
        for (int r = 0; r < 4; ++r) {
            int row = row0 + mi * 16 + q * 4 + r;
            float* dst = h2 + (size_t)row * N_CLS;
#pragma unroll
            for (int ni = 0; ni < 4; ++ni)
                dst[ni * 16 + m] = acc[mi][ni][r] + bias[ni];
        }
}

// ---------------- SpMM1 gather: h1r = bf16(relu(sum val*h0b[col])) ----------
__global__ __launch_bounds__(256) void spmm_g128_kernel(
    const int* __restrict__ rp, const int2* __restrict__ es,
    const unsigned short* __restrict__ src, unsigned short* __restrict__ dst)
{
    const int r = blockIdx.x * 4 + threadIdx.y;
    if (r >= N_NODES) return;
    const int lane = threadIdx.x;
    const int j0 = rp[r], j1 = rp[r + 1];

    float ax = 0.f, ay = 0.f;
    int j = j0;
    for (; j + 7 < j1; j += 8) {        // 8 gathers in flight
        int2 e[8];
        ushort2 u[8];
#pragma unroll
        for (int t = 0; t < 8; ++t) e[t] = es[j + t];
#pragma unroll
        for (int t = 0; t < 8; ++t)
            u[t] = ((const ushort2*)(src + (size_t)e[t].x * HID_F))[lane];
#pragma unroll
        for (int t = 0; t < 8; ++t) {
            float v = __int_as_float(e[t].y);
            ax += v * bf2f(u[t].x);
            ay += v * bf2f(u[t].y);
        }
    }
    if (j + 3 < j1) {
        int2 e[4];
        ushort2 u[4];
#pragma unroll
        for (int t = 0; t < 4; ++t) e[t] = es[j + t];
#pragma unroll
        for (int t = 0; t < 4; ++t)
            u[t] = ((const ushort2*)(src + (size_t)e[t].x * HID_F))[lane];
#pragma unroll
        for (int t = 0; t < 4; ++t) {
            float v = __int_as_float(e[t].y);
            ax += v * bf2f(u[t].x);
            ay += v * bf2f(u[t].y);
        }
        j += 4;
    }
    for (; j < j1; ++j) {
        int2 e = es[j];
        float v = __int_as_float(e.y);
        ushort2 u = ((const ushort2*)(src + (size_t)e.x * HID_F))[lane];
        ax += v * bf2f(u.x);
        ay += v * bf2f(u.y);
    }
    ushort2 o;
    o.x = f2bf(fmaxf(ax, 0.f));
    o.y = f2bf(fmaxf(ay, 0.f));
    ((ushort2*)(dst + (size_t)r * HID_F))[lane] = o;
}

// ---------------- SpMM2 gather (F=64) ----------------
__global__ __launch_bounds__(256) void spmm_g64_kernel(
    const int* __restrict__ rp, const int2* __restrict__ es,
    const float* __restrict__ src, float* __restrict__ dst)
{
    const int r = blockIdx.x * 4 + threadIdx.y;
    if (r >= N_NODES) return;
    const int lane = threadIdx.x;
    const int j0 = rp[r], j1 = rp[r + 1];

    float acc = 0.f;
    int j = j0;
    for (; j + 7 < j1; j += 8) {
        int2 e[8];
        float a[8];
#pragma unroll
        for (int t = 0; t < 8; ++t) e[t] = es[j + t];
#pragma unroll
        for (int t = 0; t < 8; ++t)
            a[t] = src[(size_t)e[t].x * N_CLS + lane];
#pragma unroll
        for (int t = 0; t < 8; ++t)
            acc += __int_as_float(e[t].y) * a[t];
    }
    if (j + 3 < j1) {
        int2 e[4];
        float a[4];
#pragma unroll
        for (int t = 0; t < 4; ++t) e[t] = es[j + t];
#pragma unroll
        for (int t = 0; t < 4; ++t)
            a[t] = src[(size_t)e[t].x * N_CLS + lane];
#pragma unroll
        for (int t = 0; t < 4; ++t)
            acc += __int_as_float(e[t].y) * a[t];
        j += 4;
    }
    for (; j < j1; ++j) {
        int2 e = es[j];
        acc += __int_as_float(e.y) * src[(size_t)e.x * N_CLS + lane];
    }
    dst[(size_t)r * N_CLS + lane] = acc;
}

extern "C" void kernel_launch(void* const* d_in, const int* in_sizes, int n_in,
                              void* d_out, int out_size, void* d_ws, size_t ws_size,
                              hipStream_t stream)
{
    const float* x       = (const float*)d_in[0];
    const int*   adj_row = (const int*)  d_in[1];
    const int*   adj_col = (const int*)  d_in[2];
    const float* adj_val = (const float*)d_in[3];
    const float* w1      = (const float*)d_in[4];
    const float* b1      = (const float*)d_in[5];
    const float* w2      = (const float*)d_in[6];
    const float* b2      = (const float*)d_in[7];
    float*       out     = (float*)d_out;

    // workspace carve-up
    char* ws = (char*)d_ws;
    unsigned short* h0b   = (unsigned short*)ws;                  // 25.6 MB
    unsigned short* h1r   = (unsigned short*)(ws + 25600000);     // 25.6 MB
    float*          h2    = (float*)(ws + 51200000);              // 25.6 MB
    int2*           es    = (int2*) (ws + 76800000);              // 12.8 MB
    int*            rp    = (int*)  (ws + 89600000);              // 400 KB + 4
    int*            cur   = (int*)  (ws + 90000016);              // 400 KB
    unsigned short* w1t   = (unsigned short*)(ws + 90400016);     // 128 KB
    int*            lex   = (int*)  (ws + 90531088);              // 400 KB
    int*            bsum  = (int*)  (ws + 90931088);              // ~1.6 KB
    unsigned short* w2t   = (unsigned short*)(ws + 90932656);     // 16 KB

    // ---- prep ----
    w1t_kernel<<<IN_F * HID_F / 256, 256, 0, stream>>>(w1, w1t);
    w2t_kernel<<<HID_F * N_CLS / 256, 256, 0, stream>>>(w2, w2t);
    zero_int_kernel<<<(N_NODES + 255) / 256, 256, 0, stream>>>(cur, N_NODES);
    hist_kernel<<<(N_EDGES + 255) / 256, 256, 0, stream>>>(adj_row, cur);
    scanA_kernel<<<N_SCAN_BLOCKS, SCAN_BLOCK, 0, stream>>>(cur, lex, bsum);
    scanB_kernel<<<1, 512, 0, stream>>>(bsum);
    scanC_kernel<<<N_SCAN_BLOCKS, SCAN_BLOCK, 0, stream>>>(lex, bsum, rp, cur);
    scatter_kernel<<<(N_EDGES + 255) / 256, 256, 0, stream>>>(
        adj_row, adj_col, adj_val, cur, es);

    // ---- conv1 ----
    gemm1_mfma_kernel<<<NB_GEMM, 512, 0, stream>>>(x, w1t, b1, h0b);
    spmm_g128_kernel<<<(N_NODES + 3) / 4, dim3(64, 4), 0, stream>>>(
        rp, es, h0b, h1r);

    // ---- conv2 ----
    gemm2_mfma_kernel<<<NB_GEMM, 512, 0, stream>>>(h1r, w2t, b2, h2);
    spmm_g64_kernel<<<(N_NODES + 3) / 4, dim3(64, 4), 0, stream>>>(
        rp, es, h2, out);
}

// Round 3
// 563.160 us; speedup vs baseline: 1.2629x; 1.1721x over previous
//
#include <hip/hip_runtime.h>
#include <hip/hip_bf16.h>

// GCN forward on MI355X — round 8: fuse independent scatter ∥ gemm1 into one
// kernel (interleaved blockIdx split) since a single stream serializes
// launches; re-tile gemm1 to 64 rows/block (grid 1563, 32KB LDS phases,
// 2-deep A prefetch); LDS-transpose gemm1 epilogue (16B stores, kills the
// 2.6x h0b write amplification); merge prep kernels.
//
//   prep:  w1t = bf16(w1^T) ∥ w2t = bf16(w2^T) ∥ hist (cur zeroed by memset)
//   scanA/B/C -> row_ptr/cursor
//   fused: scatter(es) ∥ gemm1 (h0b = bf16(x@w1+b1))
//   spmm1: h1r = bf16(relu(spmm(A, h0b)))
//   gemm2: h2 = h1r@w2t + b2
//   spmm2: out = spmm(A, h2)

constexpr int N_NODES = 100000;
constexpr int IN_F    = 512;
constexpr int HID_F   = 128;
constexpr int N_CLS   = 64;
constexpr int N_EDGES = 1600000;

constexpr int SCAN_BLOCK    = 256;
constexpr int N_SCAN_BLOCKS = (N_NODES + SCAN_BLOCK - 1) / SCAN_BLOCK;  // 391
constexpr int NB_GEMM2      = (N_NODES + 255) / 256;                    // 391

constexpr int NB_G1 = (N_NODES + 63) / 64;        // 1563 gemm1 blocks (64 rows)
constexpr int NB_SC = (N_EDGES + 1023) / 1024;    // 1563 scatter blocks
constexpr int NB_FUSED = NB_G1 + NB_SC;           // 3126

typedef __attribute__((ext_vector_type(8))) short short8;
typedef __attribute__((ext_vector_type(4))) float f32x4;

static __device__ __forceinline__ unsigned short f2bf(float x) {
    unsigned int u = __float_as_uint(x);
    unsigned int r = (u + 0x7FFFu + ((u >> 16) & 1u)) >> 16;   // RNE
    return (unsigned short)r;
}
static __device__ __forceinline__ float bf2f(unsigned short u) {
    return __uint_as_float(((unsigned int)u) << 16);
}

// ---------------- prep: w1t ∥ w2t ∥ hist (cur pre-zeroed via memset) --------
__global__ __launch_bounds__(256) void prep_kernel(
    const float* __restrict__ w1, const float* __restrict__ w2,
    const int* __restrict__ row,
    unsigned short* __restrict__ w1t, unsigned short* __restrict__ w2t,
    int* __restrict__ counts)
{
    const int bid = blockIdx.x;
    if (bid < 256) {                               // w1t: 65536 elems, n-major
        int idx = bid * 256 + threadIdx.x;
        int n = idx >> 9, k = idx & 511;
        w1t[idx] = f2bf(w1[k * HID_F + n]);
    } else if (bid < 288) {                        // w2t: 8192 elems, n-major
        int idx = (bid - 256) * 256 + threadIdx.x;
        int n = idx >> 7, k = idx & 127;
        w2t[idx] = f2bf(w2[k * N_CLS + n]);
    } else {                                       // hist
        int e = (bid - 288) * 256 + threadIdx.x;
        if (e < N_EDGES) atomicAdd(&counts[row[e]], 1);
    }
}

// ---------------- CSR scans ----------------
__global__ __launch_bounds__(SCAN_BLOCK) void scanA_kernel(
    const int* __restrict__ counts, int* __restrict__ local_ex,
    int* __restrict__ blockSums)
{
    __shared__ int s[SCAN_BLOCK];
    const int t = threadIdx.x;
    const int i = blockIdx.x * SCAN_BLOCK + t;
    int v = (i < N_NODES) ? counts[i] : 0;
    s[t] = v;
    __syncthreads();
    for (int off = 1; off < SCAN_BLOCK; off <<= 1) {
        int u = (t >= off) ? s[t - off] : 0;
        __syncthreads();
        s[t] += u;
        __syncthreads();
    }
    if (i < N_NODES) local_ex[i] = s[t] - v;
    if (t == SCAN_BLOCK - 1) blockSums[blockIdx.x] = s[t];
}

__global__ __launch_bounds__(512) void scanB_kernel(int* __restrict__ blockSums)
{
    __shared__ int s[512];
    const int t = threadIdx.x;
    int v = (t < N_SCAN_BLOCKS) ? blockSums[t] : 0;
    s[t] = v;
    __syncthreads();
    for (int off = 1; off < 512; off <<= 1) {
        int u = (t >= off) ? s[t - off] : 0;
        __syncthreads();
        s[t] += u;
        __syncthreads();
    }
    if (t < N_SCAN_BLOCKS) blockSums[t] = s[t] - v;
}

__global__ __launch_bounds__(SCAN_BLOCK) void scanC_kernel(
    const int* __restrict__ local_ex, const int* __restrict__ blockSums,
    int* __restrict__ row_ptr, int* __restrict__ cursor)
{
    const int i = blockIdx.x * SCAN_BLOCK + threadIdx.x;
    if (i < N_NODES) {
        int v = local_ex[i] + blockSums[blockIdx.x];
        row_ptr[i] = v;
        cursor[i]  = v;
    }
    if (i == 0) row_ptr[N_NODES] = N_EDGES;
}

// ---------------- fused: scatter ∥ gemm1 ------------------------------------
// bid odd  -> scatter: 1024 edges/block, 4 independent chains/thread.
// bid even -> gemm1:   64 rows/block, 4 waves x 16 rows; w1t staged in LDS in
//             4 x 32KB k-phases (XOR-swizzled); A streams from HBM with 2-deep
//             register prefetch; epilogue transposes C through LDS -> 16B
//             stores.
__global__ __launch_bounds__(256, 4) void fused_g1_scatter_kernel(
    const float* __restrict__ x, const unsigned short* __restrict__ w1t,
    const float* __restrict__ b1, unsigned short* __restrict__ h0b,
    const int* __restrict__ row, const int* __restrict__ col,
    const float* __restrict__ val, int* __restrict__ cursor,
    int2* __restrict__ es)
{
    __shared__ unsigned short Bs[128 * 128];       // 32 KB
    char* lb = (char*)Bs;
    const int tid = threadIdx.x;
    const int bid = blockIdx.x;

    if (bid & 1) {
        // ---------------- scatter ----------------
        const int base = (bid >> 1) * 1024 + tid;
#pragma unroll
        for (int i = 0; i < 4; ++i) {
            int e = base + i * 256;
            if (e < N_EDGES) {
                int r = row[e];
                int pos = atomicAdd(&cursor[r], 1);
                es[pos] = make_int2(col[e], __float_as_int(val[e]));
            }
        }
        return;
    }

    // ---------------- gemm1 ----------------
    const int gid  = bid >> 1;
    const int lane = tid & 63;
    const int w    = tid >> 6;                     // 0..3
    const int m = lane & 15;
    const int q = lane >> 4;
    const int row0 = gid * 64;
    const int myrow = row0 + w * 16 + m;
    const int arow  = (myrow < N_NODES) ? myrow : (N_NODES - 1);

    f32x4 acc[8];
#pragma unroll
    for (int ni = 0; ni < 8; ++ni)
        acc[ni] = (f32x4){0.f, 0.f, 0.f, 0.f};

    union U8 { short8 v; __hip_bfloat162 h[4]; };

    const float* ap = x + (size_t)arow * IN_F + q * 8;
    const int swz = (m & 7) << 4;

    // 2-deep A prefetch: tiles 0 and 1
    float4 a0l = ((const float4*)ap)[0];
    float4 a0h = ((const float4*)ap)[1];
    float4 a1l = ((const float4*)(ap + 32))[0];
    float4 a1h = ((const float4*)(ap + 32))[1];

#pragma unroll
    for (int t = 0; t < 16; ++t) {
        if ((t & 3) == 0) {                        // stage phase p = t>>2
            if (t) __syncthreads();                // prev phase fully consumed
            const unsigned short* src = w1t + (t >> 2) * 128;
#pragma unroll
            for (int i = 0; i < 8; ++i) {
                int c = tid + i * 256;             // 0..2047 chunks of 16B
                int n = c >> 4, k16 = c & 15;
                short8 v = *(const short8*)(src + (size_t)n * IN_F + k16 * 8);
                *(short8*)(lb + ((n * 256 + k16 * 16) ^ ((n & 7) << 4))) = v;
            }
            __syncthreads();
        }

        // prefetch A tile t+2
        float4 nl, nh;
        if (t + 2 < 16) {
            nl = ((const float4*)(ap + (t + 2) * 32))[0];
            nh = ((const float4*)(ap + (t + 2) * 32))[1];
        }

        // convert current A tile to bf16 frag
        U8 u;
        u.h[0] = __float22bfloat162_rn(make_float2(a0l.x, a0l.y));
        u.h[1] = __float22bfloat162_rn(make_float2(a0l.z, a0l.w));
        u.h[2] = __float22bfloat162_rn(make_float2(a0h.x, a0h.y));
        u.h[3] = __float22bfloat162_rn(make_float2(a0h.z, a0h.w));
        short8 av = u.v;

        const int kb = (t & 3) * 64 + q * 16;      // byte offset of k in row
#pragma unroll
        for (int ni = 0; ni < 8; ++ni) {
            int off = (((ni * 16 + m) << 8) + kb) ^ swz;
            short8 bfr = *(const short8*)(lb + off);
            acc[ni] = __builtin_amdgcn_mfma_f32_16x16x32_bf16(av, bfr, acc[ni], 0, 0, 0);
        }

        a0l = a1l; a0h = a1h; a1l = nl; a1h = nh;  // rotate prefetch regs
    }

    // ---- epilogue: transpose C through LDS -> contiguous 16B stores ----
    __syncthreads();                               // done reading Bs
    {
        float bias[8];
#pragma unroll
        for (int ni = 0; ni < 8; ++ni) bias[ni] = b1[ni * 16 + m];

        char* cb = lb + w * 4352;                  // 16 rows x 272B (16B pad)
#pragma unroll
        for (int ni = 0; ni < 8; ++ni)
#pragma unroll
            for (int r = 0; r < 4; ++r)
                *(unsigned short*)(cb + (q * 4 + r) * 272 + (ni * 16 + m) * 2) =
                    f2bf(acc[ni][r] + bias[ni]);
    }
    __syncthreads();
#pragma unroll
    for (int i = 0; i < 4; ++i) {
        int c = tid + i * 256;                     // 0..1023: 64 rows x 16 ch
        int lr = c >> 4, c16 = c & 15;
        int grow = row0 + lr;
        if (grow < N_NODES) {
            short8 v = *(const short8*)(lb + (lr >> 4) * 4352 + (lr & 15) * 272 + c16 * 16);
            *(short8*)(h0b + (size_t)grow * HID_F + c16 * 8) = v;
        }
    }
}

// ---------------- GEMM2 via MFMA: h2 = h1r @ w2 + b2 ------------------------
__global__ __launch_bounds__(512, 4) void gemm2_mfma_kernel(
    const unsigned short* __restrict__ h1r, const unsigned short* __restrict__ w2t,
    const float* __restrict__ b2, float* __restrict__ h2)
{
    __shared__ unsigned short Bs[64 * 128];        // 16 KB
    char* lb = (char*)Bs;

    const int tid  = threadIdx.x;
    const int lane = tid & 63;
    const int w    = tid >> 6;
    const int m = lane & 15;
    const int q = lane >> 4;
    const int row0 = blockIdx.x * 256 + w * 32;
    const bool active = row0 < N_NODES;

    // ---- stage w2t into LDS: [n=64][k=128], XOR ((n&7)<<4) ----
#pragma unroll
    for (int i = 0; i < 2; ++i) {
        int chunk = tid + i * 512;                 // 0..1023
        int n   = chunk >> 4;                      // 16 chunks per n-row
        int k16 = chunk & 15;
        short8 v = *(const short8*)(w2t + (size_t)n * HID_F + k16 * 8);
        *(short8*)(lb + ((n * 256 + k16 * 16) ^ ((n & 7) << 4))) = v;
    }
    __syncthreads();
    if (!active) return;                           // no barriers after this

    const unsigned short* a0p = h1r + (size_t)(row0 + m)      * HID_F + q * 8;
    const unsigned short* a1p = h1r + (size_t)(row0 + 16 + m) * HID_F + q * 8;

    short8 a0[4], a1[4];
#pragma unroll
    for (int t = 0; t < 4; ++t) {
        a0[t] = *(const short8*)(a0p + t * 32);
        a1[t] = *(const short8*)(a1p + t * 32);
    }

    f32x4 acc[2][4];
#pragma unroll
    for (int mi = 0; mi < 2; ++mi)
#pragma unroll
        for (int ni = 0; ni < 4; ++ni)
            acc[mi][ni] = (f32x4){0.f, 0.f, 0.f, 0.f};

    const int swz = (m & 7) << 4;
#pragma unroll
    for (int t = 0; t < 4; ++t) {
        const int kb = t * 64 + q * 16;
#pragma unroll
        for (int ni = 0; ni < 4; ++ni) {
            int off = (((ni * 16 + m) << 8) + kb) ^ swz;
            short8 b = *(const short8*)(lb + off);
            acc[0][ni] = __builtin_amdgcn_mfma_f32_16x16x32_bf16(a0[t], b, acc[0][ni], 0, 0, 0);
            acc[1][ni] = __builtin_amdgcn_mfma_f32_16x16x32_bf16(a1[t], b, acc[1][ni], 0, 0, 0);
        }
    }

    float bias[4];
#pragma unroll
    for (int ni = 0; ni < 4; ++ni) bias[ni] = b2[ni * 16 + m];

#pragma unroll
    for (int mi = 0; mi < 2; ++mi)
#pragma unroll
        for (int r = 0; r < 4; ++r) {
            int row = row0 + mi * 16 + q * 4 + r;
            float* dst = h2 + (size_t)row * N_CLS;
#pragma unroll
            for (int ni = 0; ni < 4; ++ni)
                dst[ni * 16 + m] = acc[mi][ni][r] + bias[ni];
        }
}

// ---------------- SpMM1 gather: h1r = bf16(relu(sum val*h0b[col])) ----------
__global__ __launch_bounds__(256) void spmm_g128_kernel(
    const int* __restrict__ rp, const int2* __restrict__ es,
    const unsigned short* __restrict__ src, unsigned short* __restrict__ dst)
{
    const int r = blockIdx.x * 4 + threadIdx.y;
    if (r >= N_NODES) return;
    const int lane = threadIdx.x;
    const int j0 = rp[r], j1 = rp[r + 1];

    float ax = 0.f, ay = 0.f;
    int j = j0;
    for (; j + 7 < j1; j += 8) {        // 8 gathers in flight
        int2 e[8];
        ushort2 u[8];
#pragma unroll
        for (int t = 0; t < 8; ++t) e[t] = es[j + t];
#pragma unroll
        for (int t = 0; t < 8; ++t)
            u[t] = ((const ushort2*)(src + (size_t)e[t].x * HID_F))[lane];
#pragma unroll
        for (int t = 0; t < 8; ++t) {
            float v = __int_as_float(e[t].y);
            ax += v * bf2f(u[t].x);
            ay += v * bf2f(u[t].y);
        }
    }
    if (j + 3 < j1) {
        int2 e[4];
        ushort2 u[4];
#pragma unroll
        for (int t = 0; t < 4; ++t) e[t] = es[j + t];
#pragma unroll
        for (int t = 0; t < 4; ++t)
            u[t] = ((const ushort2*)(src + (size_t)e[t].x * HID_F))[lane];
#pragma unroll
        for (int t = 0; t < 4; ++t) {
            float v = __int_as_float(e[t].y);
            ax += v * bf2f(u[t].x);
            ay += v * bf2f(u[t].y);
        }
        j += 4;
    }
    for (; j < j1; ++j) {
        int2 e = es[j];
        float v = __int_as_float(e.y);
        ushort2 u = ((const ushort2*)(src + (size_t)e.x * HID_F))[lane];
        ax += v * bf2f(u.x);
        ay += v * bf2f(u.y);
    }
    ushort2 o;
    o.x = f2bf(fmaxf(ax, 0.f));
    o.y = f2bf(fmaxf(ay, 0.f));
    ((ushort2*)(dst + (size_t)r * HID_F))[lane] = o;
}

// ---------------- SpMM2 gather (F=64) ----------------
__global__ __launch_bounds__(256) void spmm_g64_kernel(
    const int* __restrict__ rp, const int2* __restrict__ es,
    const float* __restrict__ src, float* __restrict__ dst)
{
    const int r = blockIdx.x * 4 + threadIdx.y;
    if (r >= N_NODES) return;
    const int lane = threadIdx.x;
    const int j0 = rp[r], j1 = rp[r + 1];

    float acc = 0.f;
    int j = j0;
    for (; j + 7 < j1; j += 8) {
        int2 e[8];
        float a[8];
#pragma unroll
        for (int t = 0; t < 8; ++t) e[t] = es[j + t];
#pragma unroll
        for (int t = 0; t < 8; ++t)
            a[t] = src[(size_t)e[t].x * N_CLS + lane];
#pragma unroll
        for (int t = 0; t < 8; ++t)
            acc += __int_as_float(e[t].y) * a[t];
    }
    if (j + 3 < j1) {
        int2 e[4];
        float a[4];
#pragma unroll
        for (int t = 0; t < 4; ++t) e[t] = es[j + t];
#pragma unroll
        for (int t = 0; t < 4; ++t)
            a[t] = src[(size_t)e[t].x * N_CLS + lane];
#pragma unroll
        for (int t = 0; t < 4; ++t)
            acc += __int_as_float(e[t].y) * a[t];
        j += 4;
    }
    for (; j < j1; ++j) {
        int2 e = es[j];
        acc += __int_as_float(e.y) * src[(size_t)e.x * N_CLS + lane];
    }
    dst[(size_t)r * N_CLS + lane] = acc;
}

extern "C" void kernel_launch(void* const* d_in, const int* in_sizes, int n_in,
                              void* d_out, int out_size, void* d_ws, size_t ws_size,
                              hipStream_t stream)
{
    const float* x       = (const float*)d_in[0];
    const int*   adj_row = (const int*)  d_in[1];
    const int*   adj_col = (const int*)  d_in[2];
    const float* adj_val = (const float*)d_in[3];
    const float* w1      = (const float*)d_in[4];
    const float* b1      = (const float*)d_in[5];
    const float* w2      = (const float*)d_in[6];
    const float* b2      = (const float*)d_in[7];
    float*       out     = (float*)d_out;

    // workspace carve-up
    char* ws = (char*)d_ws;
    unsigned short* h0b   = (unsigned short*)ws;                  // 25.6 MB
    unsigned short* h1r   = (unsigned short*)(ws + 25600000);     // 25.6 MB
    float*          h2    = (float*)(ws + 51200000);              // 25.6 MB
    int2*           es    = (int2*) (ws + 76800000);              // 12.8 MB
    int*            rp    = (int*)  (ws + 89600000);              // 400 KB + 4
    int*            cur   = (int*)  (ws + 90000016);              // 400 KB
    unsigned short* w1t   = (unsigned short*)(ws + 90400016);     // 128 KB
    int*            lex   = (int*)  (ws + 90531088);              // 400 KB
    int*            bsum  = (int*)  (ws + 90931088);              // ~1.6 KB
    unsigned short* w2t   = (unsigned short*)(ws + 90932656);     // 16 KB

    // ---- prep ----
    hipMemsetAsync(cur, 0, N_NODES * sizeof(int), stream);
    prep_kernel<<<288 + (N_EDGES + 255) / 256, 256, 0, stream>>>(
        w1, w2, adj_row, w1t, w2t, cur);
    scanA_kernel<<<N_SCAN_BLOCKS, SCAN_BLOCK, 0, stream>>>(cur, lex, bsum);
    scanB_kernel<<<1, 512, 0, stream>>>(bsum);
    scanC_kernel<<<N_SCAN_BLOCKS, SCAN_BLOCK, 0, stream>>>(lex, bsum, rp, cur);

    // ---- conv1: scatter ∥ gemm1 fused ----
    fused_g1_scatter_kernel<<<NB_FUSED, 256, 0, stream>>>(
        x, w1t, b1, h0b, adj_row, adj_col, adj_val, cur, es);
    spmm_g128_kernel<<<(N_NODES + 3) / 4, dim3(64, 4), 0, stream>>>(
        rp, es, h0b, h1r);

    // ---- conv2 ----
    gemm2_mfma_kernel<<<NB_GEMM2, 512, 0, stream>>>(h1r, w2t, b2, h2);
    spmm_g64_kernel<<<(N_NODES + 3) / 4, dim3(64, 4), 0, stream>>>(
        rp, es, h2, out);
}